// Round 6
// baseline (307.297 us; speedup 1.0000x reference)
//
#include <hip/hip_runtime.h>
#include <hip/hip_bf16.h>
#include <math.h>

#define B_TOTAL 8192
#define NN      82
#define HH      10
#define OUTC    5
#define TSTEP   3
#define NBB     2            // batches per block
#define THREADS 192
#define ROWS    (NBB * NN)   // 164
#define KP      96           // padded j dim for adjacency (3 x 32)
#define MP      16           // padded h rows per batch in Xt
#define XS      104          // Xt row stride bf16 (208 B: 16B-aligned, 8-bank-spread)
#define BVS     36           // Bv row stride bf16 (72 B: 8B-aligned, 16-bank-spread)
#define GZS     20           // Gz row stride bf16 (40 B)
#define GHS     12           // Gh row stride f32 (48 B)
#define NT_GATE 11           // ceil(164/16) gate N-tiles

typedef __bf16 bf16x8 __attribute__((ext_vector_type(8)));
typedef float  f32x4  __attribute__((ext_vector_type(4)));

__device__ __forceinline__ float sigmoid_(float x) {
    return 1.0f / (1.0f + __expf(-x));
}
__device__ __forceinline__ float tanh_(float x) {
    float e = __expf(2.0f * x);
    return 1.0f - 2.0f / (e + 1.0f);
}
__device__ __forceinline__ unsigned short bfb(__hip_bfloat16 h) {
    union { __hip_bfloat16 b; unsigned short u; } x; x.b = h; return x.u;
}
__device__ __forceinline__ unsigned pack2f(float a, float b) {
    return (unsigned)bfb(__float2bfloat16(a)) |
           ((unsigned)bfb(__float2bfloat16(b)) << 16);
}
__device__ __forceinline__ __bf16 tobf(float v) {
    union { __hip_bfloat16 b; __bf16 n; } u; u.b = __float2bfloat16(v); return u.n;
}
__device__ __forceinline__ float bfhi(float v) {   // v rounded to bf16, back to f32
    union { unsigned u; float f; } x;
    x.u = (unsigned)bfb(__float2bfloat16(v)) << 16; return x.f;
}

// adjP: 4 planes of KPxKP bf16: [0] in hi, [1] out hi, [2] in lo, [3] out lo.
__global__ void prep_adj_kernel(const float* __restrict__ in_adj,
                                const float* __restrict__ out_adj,
                                __hip_bfloat16* __restrict__ adjP) {
    int idx = blockIdx.x * blockDim.x + threadIdx.x;
    if (idx < 2 * KP * KP) {
        int a   = idx / (KP * KP);
        int rem = idx - a * (KP * KP);
        int i = rem / KP;
        int j = rem - i * KP;
        float v = 0.0f;
        if (i < NN && j < NN) v = (a == 0) ? in_adj[i * NN + j] : out_adj[i * NN + j];
        __hip_bfloat16 hi = __float2bfloat16(v);
        __hip_bfloat16 lo = __float2bfloat16(v - __bfloat162float(hi));
        adjP[idx]               = hi;
        adjP[2 * KP * KP + idx] = lo;
    }
}

extern "C" __global__ __launch_bounds__(THREADS, 3)
void ggnn_kernel(const float* __restrict__ x,
                 const __hip_bfloat16* __restrict__ adjP,
                 const float* __restrict__ w3w, const float* __restrict__ b3w,
                 const float* __restrict__ w3u, const float* __restrict__ b3u,
                 const float* __restrict__ w4w, const float* __restrict__ b4w,
                 const float* __restrict__ w5w, const float* __restrict__ b5w,
                 const float* __restrict__ w5u, const float* __restrict__ b5u,
                 const float* __restrict__ wout, const float* __restrict__ bout,
                 float* __restrict__ out0, float* __restrict__ out_fn)
{
    // node states transposed (A-operand of agg): Xt[bl*16+h][j], hi/lo
    __shared__ __align__(16) __hip_bfloat16 XtH[NBB * MP][XS];   // 6656 B
    __shared__ __align__(16) __hip_bfloat16 XtL[NBB * MP][XS];   // 6656 B
    // gate-matmul B operand: Bv[row][k]  k: 0..9 a_in, 10..19 a_out, 20..29 fn, 30..31 zero
    // 176 rows so tile-10 MFMA reads stay in-bounds (rows 164..175 garbage, C masked)
    __shared__ __align__(16) __hip_bfloat16 BvH[176][BVS];       // 12672 B
    __shared__ __align__(16) __hip_bfloat16 BvL[176][BVS];       // 12672 B
    // gate pre-activations: z/r in bf16, hpre1 (w5w.av part) in fp32
    __shared__ __align__(16) __hip_bfloat16 Gz[ROWS][GZS];       // 6560 B
    __shared__ __align__(16) float          Gh[ROWS][GHS];       // 7872 B
    // total 53,088 B -> 3 blocks/CU

    const int t     = threadIdx.x;
    const int bbase = blockIdx.x * NBB;
    const int bl    = t / NN;            // 0..1 row-active, 2 = spare
    const int node  = t - bl * NN;
    const bool act  = (t < ROWS);
    const int b     = bbase + bl;

    const int lane = t & 63;
    const int w    = t >> 6;             // wave 0..2
    const int lo16 = lane & 15;
    const int quad = lane >> 4;

    // ---- build fused gate weight A-fragments in registers (once) ----
    // W[m][k]: m 0..9 zpre = [w3w | w3u], m 10..19 rpre = [w4w | w3u]  (reference bug),
    //          m 20..29 hpre1 = [w5w | 0], zero padding elsewhere. K=32.
    bf16x8 WAh[2], WAl[2];
    #pragma unroll
    for (int mt = 0; mt < 2; ++mt) {
        int m = mt * 16 + lo16;
        #pragma unroll
        for (int j = 0; j < 8; ++j) {
            int k = quad * 8 + j;
            float wv = 0.0f;
            if (m < 30 && k < 30) {
                if (k < 20) {
                    if (m < 10)      wv = w3w[m * 20 + k];
                    else if (m < 20) wv = w4w[(m - 10) * 20 + k];
                    else             wv = w5w[(m - 20) * 20 + k];
                } else {
                    int ku = k - 20;
                    if (m < 10)      wv = w3u[m * 10 + ku];
                    else if (m < 20) wv = w3u[(m - 10) * 10 + ku];
                }
            }
            float hi = bfhi(wv);
            WAh[mt][j] = tobf(wv);
            WAl[mt][j] = tobf(wv - hi);
        }
    }

    // ---- init: fill Xt (transposed hi/lo, zero j-pad) and Bv fn-section + k-pad ----
    for (int idx = t; idx < NBB * HH * KP; idx += THREADS) {
        int b_l = idx / (HH * KP);
        int rem = idx - b_l * (HH * KP);
        int h   = rem / KP;
        int j   = rem - h * KP;
        float v = 0.0f;
        if (j < NN) v = x[((size_t)(bbase + b_l) * NN + j) * HH + h];
        __hip_bfloat16 hi = __float2bfloat16(v);
        __hip_bfloat16 lo = __float2bfloat16(v - __bfloat162float(hi));
        XtH[b_l * MP + h][j] = hi;
        XtL[b_l * MP + h][j] = lo;
        if (j < NN) {
            BvH[b_l * NN + j][20 + h] = hi;
            BvL[b_l * NN + j][20 + h] = lo;
        }
    }
    for (int r = t; r < ROWS; r += THREADS) {      // zero k 30..31 (read by MFMA quad3)
        *reinterpret_cast<unsigned*>(&BvH[r][30]) = 0u;
        *reinterpret_cast<unsigned*>(&BvL[r][30]) = 0u;
        *reinterpret_cast<unsigned*>(&BvH[r][32]) = 0u;   // padding hygiene
        *reinterpret_cast<unsigned*>(&BvL[r][32]) = 0u;
        *reinterpret_cast<unsigned*>(&BvH[r][34]) = 0u;
        *reinterpret_cast<unsigned*>(&BvL[r][34]) = 0u;
    }

    // ---- per-thread state fn from x ----
    float fn[HH];
    if (act) {
        const float* xr = x + ((size_t)b * NN + node) * HH;
        #pragma unroll
        for (int h2 = 0; h2 < HH / 2; ++h2) {
            float2 p = reinterpret_cast<const float2*>(xr)[h2];
            fn[2 * h2]     = p.x;
            fn[2 * h2 + 1] = p.y;
        }
    }
    __syncthreads();

    for (int step = 0; step < TSTEP; ++step) {
        // ================= phase 1: aggregation MFMA =================
        // A = Xt (LDS), B = adjP (global, L2-hot), C -> Bv av-section (bf16 hi/lo)
        {
            bf16x8 AH[2][3], AL[2][3];
            #pragma unroll
            for (int mt = 0; mt < 2; ++mt)
                #pragma unroll
                for (int k = 0; k < 3; ++k) {
                    AH[mt][k] = *reinterpret_cast<const bf16x8*>(&XtH[mt * MP + lo16][quad * 8 + k * 32]);
                    AL[mt][k] = *reinterpret_cast<const bf16x8*>(&XtL[mt * MP + lo16][quad * 8 + k * 32]);
                }
            #pragma unroll
            for (int c = 0; c < 4; ++c) {
                int combo = w * 4 + c;
                int nt = combo >> 1;
                int ad = combo & 1;
                const __hip_bfloat16* base = adjP + (size_t)ad * KP * KP
                                           + (size_t)(nt * 16 + lo16) * KP + quad * 8;
                bf16x8 Bh[3], Bl[3];
                #pragma unroll
                for (int k = 0; k < 3; ++k) {
                    Bh[k] = *reinterpret_cast<const bf16x8*>(base + k * 32);
                    Bl[k] = *reinterpret_cast<const bf16x8*>(base + 2 * KP * KP + k * 32);
                }
                #pragma unroll
                for (int mt = 0; mt < 2; ++mt) {
                    f32x4 acc = {0.0f, 0.0f, 0.0f, 0.0f};
                    #pragma unroll
                    for (int k = 0; k < 3; ++k) {
                        acc = __builtin_amdgcn_mfma_f32_16x16x32_bf16(AH[mt][k], Bh[k], acc, 0, 0, 0);
                        acc = __builtin_amdgcn_mfma_f32_16x16x32_bf16(AL[mt][k], Bh[k], acc, 0, 0, 0);
                        acc = __builtin_amdgcn_mfma_f32_16x16x32_bf16(AH[mt][k], Bl[k], acc, 0, 0, 0);
                    }
                    // C[m=h=quad*4+r][n=i=lo16 of tile nt] -> Bv[mt*82+i][ad*10+m], m<10
                    int i = nt * 16 + lo16;
                    if (i < NN) {
                        int rr = mt * NN + i;
                        int kb = ad * 10 + quad * 4;
                        if (quad < 2) {
                            *reinterpret_cast<unsigned*>(&BvH[rr][kb])     = pack2f(acc[0], acc[1]);
                            *reinterpret_cast<unsigned*>(&BvH[rr][kb + 2]) = pack2f(acc[2], acc[3]);
                            float l0 = acc[0] - bfhi(acc[0]), l1 = acc[1] - bfhi(acc[1]);
                            float l2 = acc[2] - bfhi(acc[2]), l3 = acc[3] - bfhi(acc[3]);
                            *reinterpret_cast<unsigned*>(&BvL[rr][kb])     = pack2f(l0, l1);
                            *reinterpret_cast<unsigned*>(&BvL[rr][kb + 2]) = pack2f(l2, l3);
                        } else if (quad == 2) {   // m = 8,9
                            *reinterpret_cast<unsigned*>(&BvH[rr][kb]) = pack2f(acc[0], acc[1]);
                            float l0 = acc[0] - bfhi(acc[0]), l1 = acc[1] - bfhi(acc[1]);
                            *reinterpret_cast<unsigned*>(&BvL[rr][kb]) = pack2f(l0, l1);
                        }
                    }
                }
            }
        }
        __syncthreads();

        // ================= phase 2: gate MFMA =================
        // A = Wfused (regs), B = Bv (LDS), C -> Gz (bf16) / Gh (fp32)
        {
            int t0 = w * 4;
            int t1 = (t0 + 4 < NT_GATE) ? t0 + 4 : NT_GATE;
            for (int tile = t0; tile < t1; ++tile) {
                int row = tile * 16 + lo16;
                uint2 h0 = *reinterpret_cast<const uint2*>(&BvH[row][quad * 8]);
                uint2 h1 = *reinterpret_cast<const uint2*>(&BvH[row][quad * 8 + 4]);
                uint2 l0 = *reinterpret_cast<const uint2*>(&BvL[row][quad * 8]);
                uint2 l1 = *reinterpret_cast<const uint2*>(&BvL[row][quad * 8 + 4]);
                union { uint4 q; bf16x8 v; } bh, bll;
                bh.q  = make_uint4(h0.x, h0.y, h1.x, h1.y);
                bll.q = make_uint4(l0.x, l0.y, l1.x, l1.y);
                #pragma unroll
                for (int mt = 0; mt < 2; ++mt) {
                    f32x4 acc = {0.0f, 0.0f, 0.0f, 0.0f};
                    acc = __builtin_amdgcn_mfma_f32_16x16x32_bf16(WAh[mt], bh.v,  acc, 0, 0, 0);
                    acc = __builtin_amdgcn_mfma_f32_16x16x32_bf16(WAl[mt], bh.v,  acc, 0, 0, 0);
                    acc = __builtin_amdgcn_mfma_f32_16x16x32_bf16(WAh[mt], bll.v, acc, 0, 0, 0);
                    if (row < ROWS) {
                        if (mt == 0) {                    // m = quad*4+r in 0..15 -> Gz
                            uint2 pk;
                            pk.x = pack2f(acc[0], acc[1]);
                            pk.y = pack2f(acc[2], acc[3]);
                            *reinterpret_cast<uint2*>(&Gz[row][quad * 4]) = pk;
                        } else {
                            if (quad == 0) {              // m 16..19 -> Gz[16..19]
                                uint2 pk;
                                pk.x = pack2f(acc[0], acc[1]);
                                pk.y = pack2f(acc[2], acc[3]);
                                *reinterpret_cast<uint2*>(&Gz[row][16]) = pk;
                            } else {                      // m 20..31 -> Gh[quad*4-4 ..]
                                *reinterpret_cast<float4*>(&Gh[row][quad * 4 - 4]) =
                                    make_float4(acc[0], acc[1], acc[2], acc[3]);
                            }
                        }
                    }
                }
            }
        }
        __syncthreads();

        // ================= phase 3: elementwise GRU glue =================
        if (act) {
            float g[20];
            const uint2* gz = reinterpret_cast<const uint2*>(&Gz[t][0]);
            #pragma unroll
            for (int p = 0; p < 5; ++p) {
                uint2 u = gz[p];
                g[4 * p + 0] = __uint_as_float(u.x << 16);
                g[4 * p + 1] = __uint_as_float(u.x & 0xffff0000u);
                g[4 * p + 2] = __uint_as_float(u.y << 16);
                g[4 * p + 3] = __uint_as_float(u.y & 0xffff0000u);
            }
            float hp[HH];
            {
                float4 a = *reinterpret_cast<const float4*>(&Gh[t][0]);
                float4 c = *reinterpret_cast<const float4*>(&Gh[t][4]);
                float2 d = *reinterpret_cast<const float2*>(&Gh[t][8]);
                hp[0]=a.x; hp[1]=a.y; hp[2]=a.z; hp[3]=a.w;
                hp[4]=c.x; hp[5]=c.y; hp[6]=c.z; hp[7]=c.w;
                hp[8]=d.x; hp[9]=d.y;
            }
            float zv[HH], rf[HH];
            #pragma unroll
            for (int h = 0; h < HH; ++h)
                zv[h] = sigmoid_(g[h] + b3w[h] + b3u[h]);
            #pragma unroll
            for (int h = 0; h < HH; ++h) {
                float rv = sigmoid_(g[10 + h] + b4w[h] + b3u[h]);   // reference bug: b3u/w3u
                rf[h] = rv * fn[h];
            }
            #pragma unroll
            for (int h = 0; h < HH; ++h) {
                float s = hp[h] + b5w[h] + b5u[h];
                #pragma unroll
                for (int k = 0; k < HH; ++k) s = fmaf(w5u[h * HH + k], rf[k], s);
                float hv = tanh_(s);
                fn[h] = fn[h] + zv[h] * (hv - fn[h]);
            }
            // publish fn': Xt (transposed, hi/lo b16) + Bv fn-section (packed b32)
            #pragma unroll
            for (int h = 0; h < HH; ++h) {
                __hip_bfloat16 hi = __float2bfloat16(fn[h]);
                __hip_bfloat16 lo = __float2bfloat16(fn[h] - __bfloat162float(hi));
                XtH[bl * MP + h][node] = hi;
                XtL[bl * MP + h][node] = lo;
            }
            #pragma unroll
            for (int p = 0; p < 5; ++p) {
                float v0 = fn[2 * p], v1 = fn[2 * p + 1];
                *reinterpret_cast<unsigned*>(&BvH[t][20 + 2 * p]) = pack2f(v0, v1);
                float l0 = v0 - bfhi(v0), l1 = v1 - bfhi(v1);
                *reinterpret_cast<unsigned*>(&BvL[t][20 + 2 * p]) = pack2f(l0, l1);
            }
        }
        __syncthreads();
    }

    // ---- epilogue: out0 = tanh([fn, x] @ wout^T + bout), out_fn = fn ----
    if (act) {
        size_t row = (size_t)b * NN + node;
        const float* xr = x + row * HH;
        float xi[HH];
        #pragma unroll
        for (int h2 = 0; h2 < HH / 2; ++h2) {
            float2 p = reinterpret_cast<const float2*>(xr)[h2];
            xi[2 * h2]     = p.x;
            xi[2 * h2 + 1] = p.y;
        }
        #pragma unroll
        for (int c = 0; c < OUTC; ++c) {
            float s = bout[c];
            #pragma unroll
            for (int k = 0; k < HH; ++k) s = fmaf(wout[c * 2 * HH + k],      fn[k], s);
            #pragma unroll
            for (int k = 0; k < HH; ++k) s = fmaf(wout[c * 2 * HH + HH + k], xi[k], s);
            out0[row * OUTC + c] = tanh_(s);
        }
        #pragma unroll
        for (int h2 = 0; h2 < HH / 2; ++h2) {
            reinterpret_cast<float2*>(out_fn + row * HH)[h2] =
                make_float2(fn[2 * h2], fn[2 * h2 + 1]);
        }
    }
}

extern "C" void kernel_launch(void* const* d_in, const int* in_sizes, int n_in,
                              void* d_out, int out_size, void* d_ws, size_t ws_size,
                              hipStream_t stream) {
    const float* x       = (const float*)d_in[0];
    const float* in_adj  = (const float*)d_in[1];
    const float* out_adj = (const float*)d_in[2];
    const float* w3w = (const float*)d_in[3];
    const float* b3w = (const float*)d_in[4];
    const float* w3u = (const float*)d_in[5];
    const float* b3u = (const float*)d_in[6];
    const float* w4w = (const float*)d_in[7];
    const float* b4w = (const float*)d_in[8];
    const float* w5w = (const float*)d_in[9];
    const float* b5w = (const float*)d_in[10];
    const float* w5u = (const float*)d_in[11];
    const float* b5u = (const float*)d_in[12];
    const float* wout = (const float*)d_in[13];
    const float* bout = (const float*)d_in[14];

    __hip_bfloat16* adjP = (__hip_bfloat16*)d_ws;   // 4*96*96*2 = 73.7 KB
    float* out0   = (float*)d_out;
    float* out_fn = out0 + (size_t)B_TOTAL * NN * OUTC;

    prep_adj_kernel<<<(2 * KP * KP + 255) / 256, 256, 0, stream>>>(in_adj, out_adj, adjP);

    ggnn_kernel<<<B_TOTAL / NBB, THREADS, 0, stream>>>(
        x, adjP, w3w, b3w, w3u, b3u, w4w, b4w, w5w, b5w, w5u, b5u,
        wout, bout, out0, out_fn);
}

// Round 7
// 227.602 us; speedup vs baseline: 1.3501x; 1.3501x over previous
//
#include <hip/hip_runtime.h>
#include <hip/hip_bf16.h>
#include <math.h>

#define B_TOTAL 8192
#define NN      82
#define HH      10
#define OUTC    5
#define TSTEP   3
#define NB      3            // batches per block
#define THREADS 256
#define KP      96           // padded K (j) dim: 3 x 32
#define MP      16           // padded per-batch row dim (h: 10 -> 16)
#define XS      104          // Xt row stride in bf16 (208 B: 16B-aligned, 8-bank-spread)
#define UTS     248          // uT plane stride in floats (>= NB*NN = 246)

typedef __bf16 bf16x8 __attribute__((ext_vector_type(8)));
typedef float  f32x4  __attribute__((ext_vector_type(4)));
typedef float  f32x2  __attribute__((ext_vector_type(2)));

__device__ __forceinline__ float sigmoid_(float x) {
    return 1.0f / (1.0f + __expf(-x));
}
__device__ __forceinline__ float tanh_(float x) {
    float e = __expf(2.0f * x);
    return 1.0f - 2.0f / (e + 1.0f);
}
__device__ __forceinline__ f32x2 ld2(const float* p) {       // 8B-aligned uniform pair
    return *reinterpret_cast<const f32x2*>(p);
}
__device__ __forceinline__ f32x2 fma2(f32x2 a, f32x2 b, f32x2 c) {
    return __builtin_elementwise_fma(a, b, c);               // -> v_pk_fma_f32
}

// adjP layout (bf16, each 96x96 zero-padded):
//   [0]: in_adj hi   [1]: out_adj hi   [2]: in_adj lo   [3]: out_adj lo
__global__ void prep_adj_kernel(const float* __restrict__ in_adj,
                                const float* __restrict__ out_adj,
                                __hip_bfloat16* __restrict__ adjP) {
    int idx = blockIdx.x * blockDim.x + threadIdx.x;
    if (idx < 2 * KP * KP) {
        int a   = idx / (KP * KP);
        int rem = idx - a * (KP * KP);
        int i = rem / KP;
        int j = rem - i * KP;
        float v = 0.0f;
        if (i < NN && j < NN) v = (a == 0) ? in_adj[i * NN + j] : out_adj[i * NN + j];
        __hip_bfloat16 hi = __float2bfloat16(v);
        __hip_bfloat16 lo = __float2bfloat16(v - __bfloat162float(hi));
        adjP[idx]               = hi;
        adjP[2 * KP * KP + idx] = lo;
    }
}

extern "C" __global__ __launch_bounds__(THREADS, 4)
void ggnn_kernel(const float* __restrict__ x,
                 const __hip_bfloat16* __restrict__ adjP,
                 const float* __restrict__ w3w, const float* __restrict__ b3w,
                 const float* __restrict__ w3u, const float* __restrict__ b3u,
                 const float* __restrict__ w4w, const float* __restrict__ b4w,
                 const float* __restrict__ w5w, const float* __restrict__ b5w,
                 const float* __restrict__ w5u, const float* __restrict__ b5u,
                 const float* __restrict__ wout, const float* __restrict__ bout,
                 float* __restrict__ out0, float* __restrict__ out_fn)
{
    // Node states transposed, bf16 hi/lo split: Xt[b_l*16 + h][j], stride XS=104
    __shared__ __align__(16) __hip_bfloat16 XtH[NB * MP][XS];   // 9984 B
    __shared__ __align__(16) __hip_bfloat16 XtL[NB * MP][XS];   // 9984 B
    // Aggregation output, TRANSPOSED planes: uT[h][col], col = b_l*NN + i.
    // GRU reads are coalesced b32 (lane=col); MFMA writes are 16-consecutive b32.
    __shared__ float uinT [HH][UTS];                            // 9920 B
    __shared__ float uoutT[HH][UTS];                            // 9920 B
    // total 39,808 B -> 4 blocks/CU

    const int t     = threadIdx.x;
    const int bbase = blockIdx.x * NB;
    const int bl    = t / NN;            // 0..2 GRU-active, 3 = spare lanes
    const int node  = t - bl * NN;
    const bool act  = (bl < NB) && (bbase + bl < B_TOTAL);
    const int b     = bbase + bl;

    const int lane = t & 63;
    const int w    = t >> 6;             // wave id 0..3
    const int lo16 = lane & 15;
    const int quad = lane >> 4;

    // ---- preload this wave's 3 (ntile,adj) B-combos into registers (step-invariant) ----
    bf16x8 Bh[3][3], Bl[3][3];           // 72 VGPRs
    int ntile_c[3], adj_c[3];
    #pragma unroll
    for (int c = 0; c < 3; ++c) {
        int co = w * 3 + c;
        int nt = co >> 1;
        int ad = co & 1;
        ntile_c[c] = nt;
        adj_c[c]   = ad;
        const __hip_bfloat16* BpH = adjP + ((size_t)ad * KP * KP
                                            + (size_t)(nt * 16 + lo16) * KP
                                            + quad * 8);
        #pragma unroll
        for (int k = 0; k < 3; ++k) {
            Bh[c][k] = *reinterpret_cast<const bf16x8*>(BpH + k * 32);
            Bl[c][k] = *reinterpret_cast<const bf16x8*>(BpH + 2 * KP * KP + k * 32);
        }
    }

    // ---- initial fill of XtH/XtL from x (coalesced read) ----
    for (int idx = t; idx < NB * NN * HH; idx += THREADS) {
        int b_l = idx / (NN * HH);
        int rem = idx - b_l * (NN * HH);
        int j   = rem / HH;
        int h   = rem - j * HH;
        size_t g = (size_t)bbase * NN * HH + idx;
        float v = (g < (size_t)B_TOTAL * NN * HH) ? x[g] : 0.0f;
        __hip_bfloat16 hi = __float2bfloat16(v);
        __hip_bfloat16 lo = __float2bfloat16(v - __bfloat162float(hi));
        XtH[b_l * MP + h][j] = hi;
        XtL[b_l * MP + h][j] = lo;
    }
    // zero the K-pad columns (j = 82..95) for every row
    for (int idx = t; idx < NB * MP * (KP - NN); idx += THREADS) {
        int r = idx / (KP - NN);
        int c = idx - r * (KP - NN);
        __hip_bfloat16 z = __float2bfloat16(0.0f);
        XtH[r][NN + c] = z;
        XtL[r][NN + c] = z;
    }

    // ---- per-thread GRU state fn (as f32x2 pairs) from x ----
    f32x2 fn2[5];
    if (act) {
        const float* xr = x + ((size_t)b * NN + node) * HH;
        #pragma unroll
        for (int p = 0; p < 5; ++p) {
            float2 v = reinterpret_cast<const float2*>(xr)[p];
            fn2[p].x = v.x; fn2[p].y = v.y;
        }
    }

    for (int step = 0; step < TSTEP; ++step) {
        __syncthreads();   // Xt writes visible

        // ---- aggregation via MFMA: A from LDS (reused across combos), B from regs ----
        #pragma unroll
        for (int mtile = 0; mtile < NB; ++mtile) {
            f32x4 acc[3] = {{0,0,0,0}, {0,0,0,0}, {0,0,0,0}};
            #pragma unroll
            for (int k = 0; k < 3; ++k) {
                bf16x8 ah = *reinterpret_cast<const bf16x8*>(&XtH[mtile * MP + lo16][quad * 8 + k * 32]);
                bf16x8 al = *reinterpret_cast<const bf16x8*>(&XtL[mtile * MP + lo16][quad * 8 + k * 32]);
                #pragma unroll
                for (int c = 0; c < 3; ++c) {
                    acc[c] = __builtin_amdgcn_mfma_f32_16x16x32_bf16(ah, Bh[c][k], acc[c], 0, 0, 0);
                    acc[c] = __builtin_amdgcn_mfma_f32_16x16x32_bf16(al, Bh[c][k], acc[c], 0, 0, 0);
                    acc[c] = __builtin_amdgcn_mfma_f32_16x16x32_bf16(ah, Bl[c][k], acc[c], 0, 0, 0);
                }
            }
            // C element (reg r): row h = quad*4+r, col i = ntile*16+lo16 (valid h<10, i<82)
            #pragma unroll
            for (int c = 0; c < 3; ++c) {
                int i = ntile_c[c] * 16 + lo16;
                if (i < NN) {
                    int col = mtile * NN + i;
                    float* plane0 = adj_c[c] ? &uoutT[0][0] : &uinT[0][0];
                    if (quad < 2) {
                        #pragma unroll
                        for (int r = 0; r < 4; ++r)
                            plane0[(quad * 4 + r) * UTS + col] = acc[c][r];
                    } else if (quad == 2) {
                        plane0[8 * UTS + col] = acc[c][0];
                        plane0[9 * UTS + col] = acc[c][1];
                    }
                }
            }
        }

        __syncthreads();   // uT visible

        // ---- per-thread GRU (packed f32x2 over k) ----
        if (act) {
            // av pairs: av2[0..4] = a_in pairs, av2[5..9] = a_out pairs
            f32x2 av2[10];
            #pragma unroll
            for (int p = 0; p < 5; ++p) {
                av2[p].x     = uinT [2 * p][t];
                av2[p].y     = uinT [2 * p + 1][t];
                av2[5 + p].x = uoutT[2 * p][t];
                av2[5 + p].y = uoutT[2 * p + 1][t];
            }

            // u3[h] = b3u[h] + w3u[h,:].fn   (shared by zv and rv — reference bug)
            float u3[HH];
            #pragma unroll
            for (int h = 0; h < HH; ++h) {
                f32x2 s2 = {0.0f, 0.0f};
                #pragma unroll
                for (int p = 0; p < 5; ++p)
                    s2 = fma2(ld2(w3u + h * HH + 2 * p), fn2[p], s2);
                u3[h] = b3u[h] + s2.x + s2.y;
            }

            float zv[HH];
            f32x2 rf2[5];
            #pragma unroll
            for (int h = 0; h < HH; ++h) {
                f32x2 z2 = {0.0f, 0.0f}, r2 = {0.0f, 0.0f};
                #pragma unroll
                for (int p = 0; p < 10; ++p) {
                    z2 = fma2(ld2(w3w + h * 20 + 2 * p), av2[p], z2);
                    r2 = fma2(ld2(w4w + h * 20 + 2 * p), av2[p], r2);
                }
                zv[h] = sigmoid_(b3w[h] + z2.x + z2.y + u3[h]);
                float rv = sigmoid_(b4w[h] + r2.x + r2.y + u3[h]);
                float fnh = (h & 1) ? fn2[h >> 1].y : fn2[h >> 1].x;
                if (h & 1) rf2[h >> 1].y = rv * fnh; else rf2[h >> 1].x = rv * fnh;
            }

            #pragma unroll
            for (int h = 0; h < HH; ++h) {
                f32x2 s2 = {0.0f, 0.0f};
                #pragma unroll
                for (int p = 0; p < 10; ++p)
                    s2 = fma2(ld2(w5w + h * 20 + 2 * p), av2[p], s2);
                #pragma unroll
                for (int p = 0; p < 5; ++p)
                    s2 = fma2(ld2(w5u + h * HH + 2 * p), rf2[p], s2);
                float hv = tanh_(b5w[h] + b5u[h] + s2.x + s2.y);
                float fnh = (h & 1) ? fn2[h >> 1].y : fn2[h >> 1].x;
                fnh = fnh + zv[h] * (hv - fnh);
                if (h & 1) fn2[h >> 1].y = fnh; else fn2[h >> 1].x = fnh;
            }

            // publish new state into Xt (hi/lo) for next step's aggregation
            #pragma unroll
            for (int h = 0; h < HH; ++h) {
                float fnh = (h & 1) ? fn2[h >> 1].y : fn2[h >> 1].x;
                __hip_bfloat16 hi = __float2bfloat16(fnh);
                __hip_bfloat16 lo = __float2bfloat16(fnh - __bfloat162float(hi));
                XtH[bl * MP + h][node] = hi;
                XtL[bl * MP + h][node] = lo;
            }
        }
    }

    // ---- epilogue: out0 = tanh([fn, x] @ wout^T + bout), out_fn = fn ----
    if (act) {
        size_t row = (size_t)b * NN + node;
        const float* xr = x + row * HH;
        f32x2 xi2[5];
        #pragma unroll
        for (int p = 0; p < 5; ++p) {
            float2 v = reinterpret_cast<const float2*>(xr)[p];
            xi2[p].x = v.x; xi2[p].y = v.y;
        }

        #pragma unroll
        for (int c = 0; c < OUTC; ++c) {
            f32x2 s2 = {0.0f, 0.0f};
            #pragma unroll
            for (int p = 0; p < 5; ++p) {
                s2 = fma2(ld2(wout + c * 20 + 2 * p),      fn2[p], s2);
                s2 = fma2(ld2(wout + c * 20 + 10 + 2 * p), xi2[p], s2);
            }
            out0[row * OUTC + c] = tanh_(bout[c] + s2.x + s2.y);
        }
        #pragma unroll
        for (int p = 0; p < 5; ++p) {
            reinterpret_cast<float2*>(out_fn + row * HH)[p] =
                make_float2(fn2[p].x, fn2[p].y);
        }
    }
}

extern "C" void kernel_launch(void* const* d_in, const int* in_sizes, int n_in,
                              void* d_out, int out_size, void* d_ws, size_t ws_size,
                              hipStream_t stream) {
    const float* x       = (const float*)d_in[0];
    const float* in_adj  = (const float*)d_in[1];
    const float* out_adj = (const float*)d_in[2];
    const float* w3w = (const float*)d_in[3];
    const float* b3w = (const float*)d_in[4];
    const float* w3u = (const float*)d_in[5];
    const float* b3u = (const float*)d_in[6];
    const float* w4w = (const float*)d_in[7];
    const float* b4w = (const float*)d_in[8];
    const float* w5w = (const float*)d_in[9];
    const float* b5w = (const float*)d_in[10];
    const float* w5u = (const float*)d_in[11];
    const float* b5u = (const float*)d_in[12];
    const float* wout = (const float*)d_in[13];
    const float* bout = (const float*)d_in[14];

    __hip_bfloat16* adjP = (__hip_bfloat16*)d_ws;   // 4*96*96*2 = 73.7 KB
    float* out0   = (float*)d_out;
    float* out_fn = out0 + (size_t)B_TOTAL * NN * OUTC;

    prep_adj_kernel<<<(2 * KP * KP + 255) / 256, 256, 0, stream>>>(in_adj, out_adj, adjP);

    int grid = (B_TOTAL + NB - 1) / NB;             // 2731
    ggnn_kernel<<<grid, THREADS, 0, stream>>>(
        x, adjP, w3w, b3w, w3u, b3u, w4w, b4w, w5w, b5w, w5u, b5u,
        wout, bout, out0, out_fn);
}